// Round 12
// baseline (4202.090 us; speedup 1.0000x reference)
//
#include <hip/hip_runtime.h>
#include <stdint.h>

// L=512, B=32, D=H=256
// Workspace (float offsets into 64MB d_ws):
//   Eq  f16[16384*256] @ 0
//   Ev  f16[16384*256] @ 2097152
//   VT  f16[32][256][512] @ 4194304
//   S   f32[32*512*512] @ 6291456 .. 14680064  (raw scores; softmax in ctxsm_k)
//   C   f32[16384*256] @ 0          (reuse Eq+Ev, dead after score)
//   Gi2 f16[16384*768] @ 6291456    (reuse S low half, dead after ctxsm)
//   hx  f32[32][2][2][128] @ 14680064   (gru pair-exchange; PAST S's end —
//                                        R10 bug: was INSIDE S, score_k
//                                        overwrote the zeroed flags)
//   flags u32[64] @ 14696448            (memset each launch, in-graph)

#define C2    2.8853900817779268f   // 2*log2(e)
#define LOG2E 1.4426950408889634f

typedef __fp16 f16x2 __attribute__((ext_vector_type(2)));
typedef __fp16 f16x4_t __attribute__((ext_vector_type(4)));
typedef __fp16 f16x8 __attribute__((ext_vector_type(8)));
typedef float f32x4 __attribute__((ext_vector_type(4)));

static __device__ __forceinline__ float rcp_f(float x)  { return __builtin_amdgcn_rcpf(x); }
static __device__ __forceinline__ float exp2_f(float x) { return __builtin_amdgcn_exp2f(x); }
#if __has_builtin(__builtin_amdgcn_rcph)
static __device__ __forceinline__ __fp16 rcph(__fp16 x) {
  return (__fp16)__builtin_amdgcn_rcph((_Float16)x);
}
#else
static __device__ __forceinline__ __fp16 rcph(__fp16 x) {
  return (__fp16)__builtin_amdgcn_rcpf((float)x);
}
#endif
static __device__ __forceinline__ float dot2f(f16x2 a, f16x2 b, float c) {
  return __builtin_amdgcn_fdot2(a, b, c, false);
}
static __device__ __forceinline__ f16x8 cvt8(float4 a, float4 b) {
  f16x8 f;
  f[0] = (__fp16)a.x; f[1] = (__fp16)a.y; f[2] = (__fp16)a.z; f[3] = (__fp16)a.w;
  f[4] = (__fp16)b.x; f[5] = (__fp16)b.y; f[6] = (__fp16)b.z; f[7] = (__fp16)b.w;
  return f;
}

// Fragment conventions (verified end-to-end):
//   A-frag: lane(col=lane&15, quad=lane>>4) holds A[m=col][k=quad*8+jj]
//   B-frag: lane holds B[k=quad*8+jj][n=col]
//   C/D:    row(m)=quad*4+reg, col(n)=lane&15

// ---------------------------------------------------------------------------
// Fused projections -> f16 with exponent clamp to f16-normal range.
// ---------------------------------------------------------------------------
__global__ __launch_bounds__(256) void proj_k(
    const float* __restrict__ v, const float* __restrict__ Wp,
    const float* __restrict__ Wp_, __fp16* __restrict__ Eq,
    __fp16* __restrict__ Ev)
{
  __shared__ __align__(16) __fp16 As[64][40];
  __shared__ __align__(16) __fp16 Wqs[64][40];
  __shared__ __align__(16) __fp16 Wvs[64][40];
  const int t = threadIdx.x, wave = t >> 6, lane = t & 63;
  const int quad = lane >> 4, col = lane & 15;
  const int n0 = blockIdx.x * 64, m0 = blockIdx.y * 64;
  const int srow = t >> 2, skq = t & 3;

  f32x4 accq[4], accv[4];
#pragma unroll
  for (int nt = 0; nt < 4; ++nt) {
    accq[nt] = (f32x4){0.f, 0.f, 0.f, 0.f};
    accv[nt] = (f32x4){0.f, 0.f, 0.f, 0.f};
  }

  for (int kc = 0; kc < 8; ++kc) {
    const int k0 = kc * 32;
    {
      const float4* ap = (const float4*)&v[(size_t)(m0 + srow) * 256 + k0 + skq * 8];
      *(f16x8*)&As[srow][skq * 8] = cvt8(ap[0], ap[1]);
      const float4* qp = (const float4*)&Wp[(size_t)(n0 + srow) * 256 + k0 + skq * 8];
      *(f16x8*)&Wqs[srow][skq * 8] = cvt8(qp[0], qp[1]);
      const float4* vp = (const float4*)&Wp_[(size_t)(n0 + srow) * 256 + k0 + skq * 8];
      *(f16x8*)&Wvs[srow][skq * 8] = cvt8(vp[0], vp[1]);
    }
    __syncthreads();
    f16x8 a = *(const f16x8*)&As[wave * 16 + col][quad * 8];
#pragma unroll
    for (int nt = 0; nt < 4; ++nt) {
      f16x8 bq = *(const f16x8*)&Wqs[nt * 16 + col][quad * 8];
      f16x8 bv = *(const f16x8*)&Wvs[nt * 16 + col][quad * 8];
      accq[nt] = __builtin_amdgcn_mfma_f32_16x16x32_f16(a, bq, accq[nt], 0, 0, 0);
      accv[nt] = __builtin_amdgcn_mfma_f32_16x16x32_f16(a, bv, accv[nt], 0, 0, 0);
    }
    __syncthreads();
  }

#pragma unroll
  for (int nt = 0; nt < 4; ++nt)
#pragma unroll
    for (int r = 0; r < 4; ++r) {
      size_t m = m0 + wave * 16 + quad * 4 + r;
      size_t n = n0 + nt * 16 + col;
      float eq = C2 * accq[nt][r], ev = C2 * accv[nt][r];
      eq = fminf(fmaxf(eq, -14.f), 15.5f);
      ev = fminf(fmaxf(ev, -14.f), 15.5f);
      Eq[m * 256 + n] = (__fp16)exp2_f(eq);
      Ev[m * 256 + n] = (__fp16)exp2_f(ev);
    }
}

// ---------------------------------------------------------------------------
// v transpose: VT[b][d][l] (f16) from v[l][b][d] (f32). 32x32 LDS tiles.
// ---------------------------------------------------------------------------
__global__ __launch_bounds__(256) void vt_k(
    const float* __restrict__ v, __fp16* __restrict__ VT)
{
  __shared__ float Ts[32][33];
  const int t = threadIdx.x;
  const int d0 = blockIdx.x * 32, l0 = blockIdx.y * 32, b = blockIdx.z;
  {
    int lrow = t >> 3, dq = t & 7;
    float4 a = *(const float4*)&v[((size_t)(l0 + lrow) * 32 + b) * 256 + d0 + dq * 4];
    Ts[dq * 4 + 0][lrow] = a.x; Ts[dq * 4 + 1][lrow] = a.y;
    Ts[dq * 4 + 2][lrow] = a.z; Ts[dq * 4 + 3][lrow] = a.w;
  }
  __syncthreads();
  {
    int drow = t >> 3, lq = t & 7;
    f16x4_t o;
#pragma unroll
    for (int e = 0; e < 4; ++e) o[e] = (__fp16)Ts[drow][lq * 4 + e];
    *(f16x4_t*)&VT[((size_t)b * 256 + d0 + drow) * 512 + l0 + lq * 4] = o;
  }
}

// ---------------------------------------------------------------------------
// Packed-f16 score: S[b][i][l] = -2 * sum_h V[b][h] * rcp(1 + Eq*Ev).
// ---------------------------------------------------------------------------
__global__ __launch_bounds__(256) void score_k(
    const __fp16* __restrict__ Eq, const __fp16* __restrict__ Ev,
    const float* __restrict__ Vvec, float* __restrict__ S)
{
  __shared__ __align__(16) __fp16 Eqs[64][72];
  __shared__ __align__(16) __fp16 Evs[32][72];
  __shared__ __align__(16) __fp16 Vs[256];
  const int t = threadIdx.x;
  const int tx = t & 15, ty = t >> 4;
  const int l0 = blockIdx.x * 32;
  const int i0 = blockIdx.y * 64;
  const int b  = blockIdx.z;

  Vs[t] = (__fp16)(-2.0f * Vvec[b * 256 + t]);
  float acc[4][2] = {};
  const f16x2 one2 = {(__fp16)1.f, (__fp16)1.f};

  for (int st = 0; st < 4; ++st) {
    const int h0 = st * 64;
#pragma unroll
    for (int s = 0; s < 2; ++s) {
      int f = t + s * 256;
      int row = f >> 3, cq = f & 7;
      *(f16x8*)&Eqs[row][cq * 8] =
          *(const f16x8*)&Eq[((size_t)(i0 + row) * 32 + b) * 256 + h0 + cq * 8];
    }
    {
      int row = t >> 3, cq = t & 7;
      *(f16x8*)&Evs[row][cq * 8] =
          *(const f16x8*)&Ev[((size_t)(l0 + row) * 32 + b) * 256 + h0 + cq * 8];
    }
    __syncthreads();

#pragma unroll
    for (int k8 = 0; k8 < 8; ++k8) {
      f16x8 vh8 = *(const f16x8*)&Vs[h0 + k8 * 8];
      f16x8 ev80 = *(const f16x8*)&Evs[tx][k8 * 8];
      f16x8 ev81 = *(const f16x8*)&Evs[tx + 16][k8 * 8];
      f16x8 eq8[4];
#pragma unroll
      for (int r = 0; r < 4; ++r)
        eq8[r] = *(const f16x8*)&Eqs[ty * 4 + r][k8 * 8];
#pragma unroll
      for (int q = 0; q < 4; ++q) {
        f16x2 vh2 = {vh8[q * 2], vh8[q * 2 + 1]};
        f16x2 e0  = {ev80[q * 2], ev80[q * 2 + 1]};
        f16x2 e1  = {ev81[q * 2], ev81[q * 2 + 1]};
#pragma unroll
        for (int r = 0; r < 4; ++r) {
          f16x2 eq2 = {eq8[r][q * 2], eq8[r][q * 2 + 1]};
          f16x2 d0 = eq2 * e0 + one2;   // v_pk_fma_f16
          f16x2 d1 = eq2 * e1 + one2;
          f16x2 r0 = {rcph(d0[0]), rcph(d0[1])};
          f16x2 r1 = {rcph(d1[0]), rcph(d1[1])};
          acc[r][0] = dot2f(vh2, r0, acc[r][0]);
          acc[r][1] = dot2f(vh2, r1, acc[r][1]);
        }
      }
    }
    __syncthreads();
  }

#pragma unroll
  for (int r = 0; r < 4; ++r) {
    float* ps = &S[((size_t)b * 512 + i0 + ty * 4 + r) * 512 + l0];
    ps[tx]      = acc[r][0];
    ps[tx + 16] = acc[r][1];
  }
}

// ---------------------------------------------------------------------------
// FUSED softmax + context: C[i][b][d] = sum_l softmax_l(S[b][i][:])[l] * VT[b][d][l].
// ---------------------------------------------------------------------------
__global__ __launch_bounds__(512) void ctxsm_k(
    const float* __restrict__ S, const __fp16* __restrict__ VT,
    float* __restrict__ C)
{
  __shared__ __align__(16) __fp16 As[64][40];
  __shared__ __align__(16) __fp16 Vs[256][40];
  __shared__ float red[64][8];
  __shared__ float stat_m[64], stat_inv[64];
  const int t = threadIdx.x, wave = t >> 6, lane = t & 63;
  const int quad = lane >> 4, col = lane & 15;
  const int i0 = blockIdx.x * 64, b = blockIdx.y;
  const int mt = wave & 3, nh = wave >> 2;

  // ---- phase 1: row stats ----
  {
    const int row = t >> 3, seg = t & 7;
    const float* sp = &S[((size_t)b * 512 + i0 + row) * 512 + seg * 64];
    float m = -1e30f;
#pragma unroll
    for (int u = 0; u < 16; ++u) {
      float4 x = *(const float4*)&sp[u * 4];
      m = fmaxf(m, fmaxf(fmaxf(x.x, x.y), fmaxf(x.z, x.w)));
    }
    red[row][seg] = m;
    __syncthreads();
    if (seg == 0) {
      float mm = red[row][0];
#pragma unroll
      for (int u = 1; u < 8; ++u) mm = fmaxf(mm, red[row][u]);
      stat_m[row] = mm;
    }
    __syncthreads();
    float M = stat_m[row];
    float s = 0.f;
#pragma unroll
    for (int u = 0; u < 16; ++u) {
      float4 x = *(const float4*)&sp[u * 4];
      s += exp2_f(LOG2E * (x.x - M)) + exp2_f(LOG2E * (x.y - M)) +
           exp2_f(LOG2E * (x.z - M)) + exp2_f(LOG2E * (x.w - M));
    }
    red[row][seg] = s;
    __syncthreads();
    if (seg == 0) {
      float ss = red[row][0];
#pragma unroll
      for (int u = 1; u < 8; ++u) ss += red[row][u];
      stat_inv[row] = rcp_f(ss);
    }
    __syncthreads();
  }

  // ---- phase 2: MFMA with softmax applied at A staging ----
  f32x4 acc[8];
#pragma unroll
  for (int n = 0; n < 8; ++n) acc[n] = (f32x4){0.f, 0.f, 0.f, 0.f};

  for (int kc = 0; kc < 16; ++kc) {
    const int l0 = kc * 32;
    {
      int arow = t >> 3, aq = t & 7;
      float M = stat_m[arow], inv = stat_inv[arow];
      float4 x = *(const float4*)&S[((size_t)b * 512 + i0 + arow) * 512 + l0 + aq * 4];
      f16x4_t o;
      o[0] = (__fp16)(exp2_f(LOG2E * (x.x - M)) * inv);
      o[1] = (__fp16)(exp2_f(LOG2E * (x.y - M)) * inv);
      o[2] = (__fp16)(exp2_f(LOG2E * (x.z - M)) * inv);
      o[3] = (__fp16)(exp2_f(LOG2E * (x.w - M)) * inv);
      *(f16x4_t*)&As[arow][aq * 4] = o;
#pragma unroll
      for (int s2 = 0; s2 < 2; ++s2) {
        int f = t + s2 * 512;
        int vrow = f >> 2, vq = f & 3;
        *(f16x8*)&Vs[vrow][vq * 8] =
            *(const f16x8*)&VT[((size_t)b * 256 + vrow) * 512 + l0 + vq * 8];
      }
    }
    __syncthreads();
    f16x8 a = *(const f16x8*)&As[mt * 16 + col][quad * 8];
#pragma unroll
    for (int n = 0; n < 8; ++n) {
      f16x8 vf = *(const f16x8*)&Vs[nh * 128 + n * 16 + col][quad * 8];
      acc[n] = __builtin_amdgcn_mfma_f32_16x16x32_f16(a, vf, acc[n], 0, 0, 0);
    }
    __syncthreads();
  }

#pragma unroll
  for (int n = 0; n < 8; ++n)
#pragma unroll
    for (int r = 0; r < 4; ++r) {
      size_t i = i0 + mt * 16 + quad * 4 + r;
      size_t d = nh * 128 + n * 16 + col;
      C[(i * 32 + b) * 256 + d] = acc[n][r];
    }
}

// ---------------------------------------------------------------------------
// Gi2 = f16( C @ Wih^T + bih (+bhh for gates r,z) ). M=16384, N=768, K=256.
// ---------------------------------------------------------------------------
__global__ __launch_bounds__(256) void gi_k(
    const float* __restrict__ A, const float* __restrict__ W,
    const float* __restrict__ bih, const float* __restrict__ bhh,
    __fp16* __restrict__ G)
{
  __shared__ __align__(16) __fp16 As[64][40];
  __shared__ __align__(16) __fp16 Ws[64][40];
  const int t = threadIdx.x, wave = t >> 6, lane = t & 63;
  const int quad = lane >> 4, col = lane & 15;
  const int n0 = blockIdx.x * 64, m0 = blockIdx.y * 64;
  const int srow = t >> 2, skq = t & 3;

  f32x4 acc[4];
#pragma unroll
  for (int nt = 0; nt < 4; ++nt) acc[nt] = (f32x4){0.f, 0.f, 0.f, 0.f};

  for (int kc = 0; kc < 8; ++kc) {
    const int k0 = kc * 32;
    {
      const float4* ap = (const float4*)&A[(size_t)(m0 + srow) * 256 + k0 + skq * 8];
      *(f16x8*)&As[srow][skq * 8] = cvt8(ap[0], ap[1]);
      const float4* wp = (const float4*)&W[(size_t)(n0 + srow) * 256 + k0 + skq * 8];
      *(f16x8*)&Ws[srow][skq * 8] = cvt8(wp[0], wp[1]);
    }
    __syncthreads();
    f16x8 a = *(const f16x8*)&As[wave * 16 + col][quad * 8];
#pragma unroll
    for (int nt = 0; nt < 4; ++nt) {
      f16x8 b = *(const f16x8*)&Ws[nt * 16 + col][quad * 8];
      acc[nt] = __builtin_amdgcn_mfma_f32_16x16x32_f16(a, b, acc[nt], 0, 0, 0);
    }
    __syncthreads();
  }

#pragma unroll
  for (int nt = 0; nt < 4; ++nt) {
    int n = n0 + nt * 16 + col;
    float bias = bih[n] + (n < 512 ? bhh[n] : 0.f);
#pragma unroll
    for (int r = 0; r < 4; ++r) {
      size_t m = m0 + wave * 16 + quad * 4 + r;
      G[m * 768 + n] = (__fp16)(acc[nt][r] + bias);
    }
  }
}

// ---------------------------------------------------------------------------
// R11 = R10 pair-split GRU with the WORKSPACE OVERLAP FIXED.
// R10 bug: hx/flags were placed at float offsets 13631488/13664256 — INSIDE
// S's footprint (S spans 6291456..14680064). score_k overwrote the zeroed
// flags with score data (reinterpreted floats >> 512), so the acquire-poll
// was always satisfied and consumers read hx before the partner published:
// intermittent wrong exchange (passed direct run, failed graph replay).
// Fix: hx @ 14680064 (just past S), flags @ 14696448 — nothing else writes
// there. Protocol unchanged (re-audited sound):
//   publish: writers store h-half (agent relaxed), vmcnt(0)+barrier,
//            t0 flag=i+1 (release).
//   consume: t<128 acquire-polls partner flag>=i (bounded spin), issues
//            loads, own-k MFMAs hide latency, stage to hA, barrier,
//            partner-k MFMAs.
// 192 MFMA/iter/CU = 931 cyc (half of R9's 1862 floor).
// ---------------------------------------------------------------------------
__global__ __launch_bounds__(512, 1) void gru2_k(
    const __fp16* __restrict__ Gi2, const float* __restrict__ Whh,
    const float* __restrict__ bhh, const float* __restrict__ h0,
    float* __restrict__ out, float* __restrict__ hx,
    unsigned* __restrict__ flags)
{
  __shared__ __align__(16) __fp16 hA[2][256];
  const int t = threadIdx.x, wave = t >> 6, lane = t & 63;
  const int quad = lane >> 4, col = lane & 15;
  const int bid = (int)blockIdx.x;
  const int b = bid & 31, ph = bid >> 5;
  const int ja = ph * 128 + wave * 16 + col;   // this lane's output j
  const bool writer = (quad == 0);
  const int ownk = ph * 4;                     // own kc range (own h half)
  const int prtk = (ph ^ 1) * 4;               // partner kc range
  const int pbase = (ph ^ 1) * 128;            // partner j base
  float* myhx = &hx[((size_t)(b * 2 + ph)) * 256];        // [2][128]
  const float* prthx = &hx[((size_t)(b * 2 + (ph ^ 1))) * 256];
  unsigned* myflag = &flags[b * 2 + ph];
  const unsigned* prtflag = &flags[b * 2 + (ph ^ 1)];

  // B-fragments: 16 j columns per wave x 3 gates x 8 kc = 24 frags (96 regs)
  f16x8 Bf[3][8];
#pragma unroll
  for (int g = 0; g < 3; ++g) {
    const float* wrow = &Whh[(size_t)(g * 256 + ja) * 256];
#pragma unroll
    for (int kk = 0; kk < 8; ++kk) {
      const float4* wp = (const float4*)&wrow[kk * 32 + quad * 8];
      Bf[g][kk] = cvt8(wp[0], wp[1]);
    }
  }

  const float bn = bhh[512 + ja];
  float hold = h0[(size_t)b * 256 + ja];
  if (t < 256) hA[0][t] = (__fp16)h0[(size_t)b * 256 + t];  // full h_0
  __syncthreads();

  // Gi2[(i*32+b)*768 + g*256 + ja]; row stride 24576 halfs.
  const __fp16* gp = &Gi2[(size_t)b * 768 + ja];
  __fp16 gcur[3];
#pragma unroll
  for (int g = 0; g < 3; ++g) gcur[g] = gp[g * 256];
  const __fp16* gq = gp + 24576;

  float* outp = &out[(size_t)b * 256 + ja];

  for (int i = 0; i < 512; ++i) {
    // prefetch next Gi2 row (i=511 reads one dead row; in-workspace)
    __fp16 gnext[3];
    gnext[0] = gq[0];
    gnext[1] = gq[256];
    gnext[2] = gq[512];
    gq += 24576;

    // ---- exchange-issue: fetch partner half of h_i (published flag>=i) ----
    float pv = 0.f;
    if (i > 0 && t < 128) {
      const unsigned tgt = (unsigned)i;
      int sp = 0;
      while (__hip_atomic_load(prtflag, __ATOMIC_ACQUIRE,
                               __HIP_MEMORY_SCOPE_AGENT) < tgt) {
        if (++sp > 100000000) break;   // bounded: no hang mode
      }
      pv = __hip_atomic_load(&prthx[(i & 1) * 128 + t], __ATOMIC_RELAXED,
                             __HIP_MEMORY_SCOPE_AGENT);
    }

    const __fp16* hbuf = hA[i & 1];

    // ---- own-k-half MFMAs (hide the exchange loads) ----
    f32x4 acc[3];
    {
      f16x8 a = *(const f16x8*)&hbuf[ownk * 32 + quad * 8];
#pragma unroll
      for (int g = 0; g < 3; ++g)
        acc[g] = __builtin_amdgcn_mfma_f32_16x16x32_f16(
            a, Bf[g][ownk], (f32x4){0.f, 0.f, 0.f, 0.f}, 0, 0, 0);
    }
#pragma unroll
    for (int kk = 1; kk < 4; ++kk) {
      const int kc = ownk + kk;
      f16x8 a = *(const f16x8*)&hbuf[kc * 32 + quad * 8];
#pragma unroll
      for (int g = 0; g < 3; ++g)
        acc[g] = __builtin_amdgcn_mfma_f32_16x16x32_f16(
            a, Bf[g][kc], acc[g], 0, 0, 0);
    }

    // ---- stage partner half of h_i, then partner-k MFMAs ----
    if (i > 0 && t < 128) hA[i & 1][pbase + t] = (__fp16)pv;
    asm volatile("s_waitcnt lgkmcnt(0)" ::: "memory");
    __builtin_amdgcn_s_barrier();
    asm volatile("" ::: "memory");
#pragma unroll
    for (int kk = 0; kk < 4; ++kk) {
      const int kc = prtk + kk;
      f16x8 a = *(const f16x8*)&hbuf[kc * 32 + quad * 8];
#pragma unroll
      for (int g = 0; g < 3; ++g)
        acc[g] = __builtin_amdgcn_mfma_f32_16x16x32_f16(
            a, Bf[g][kc], acc[g], 0, 0, 0);
    }

    // ---- gates (all quads redundant for this wave's 16 j; no divergence) --
    float ar = acc[0][0], az = acc[1][0], an = acc[2][0];
    float rr = rcp_f(1.f + exp2_f(-LOG2E * ((float)gcur[0] + ar)));
    float zz = rcp_f(1.f + exp2_f(-LOG2E * ((float)gcur[1] + az)));
    float na = fmaf(rr, an + bn, (float)gcur[2]);
    float nn = fmaf(-2.f, rcp_f(1.f + exp2_f(C2 * na)), 1.f);
    float h  = fmaf(zz, hold - nn, nn);
    hold = h;

    if (writer) {
      outp[0] = h;
      hA[(i + 1) & 1][ja] = (__fp16)h;
      __hip_atomic_store(&myhx[((i + 1) & 1) * 128 + (wave * 16 + col)], h,
                         __ATOMIC_RELAXED, __HIP_MEMORY_SCOPE_AGENT);
    }
    outp += 8192;
    gcur[0] = gnext[0]; gcur[1] = gnext[1]; gcur[2] = gnext[2];

    // ---- publish: drain stores, block-wide sync, then release flag ----
    asm volatile("s_waitcnt vmcnt(0) lgkmcnt(0)" ::: "memory");
    __builtin_amdgcn_s_barrier();
    asm volatile("" ::: "memory");
    if (t == 0)
      __hip_atomic_store(myflag, (unsigned)(i + 1), __ATOMIC_RELEASE,
                         __HIP_MEMORY_SCOPE_AGENT);
  }
}

// ---------------------------------------------------------------------------
extern "C" void kernel_launch(void* const* d_in, const int* in_sizes, int n_in,
                              void* d_out, int out_size, void* d_ws, size_t ws_size,
                              hipStream_t stream)
{
  const float* v   = (const float*)d_in[0];
  const float* h0  = (const float*)d_in[1];
  const float* Vv  = (const float*)d_in[2];
  const float* Wp  = (const float*)d_in[3];
  const float* Wp_ = (const float*)d_in[4];
  const float* Wih = (const float*)d_in[5];
  const float* Whh = (const float*)d_in[6];
  const float* bih = (const float*)d_in[7];
  const float* bhh = (const float*)d_in[8];
  float* out = (float*)d_out;
  float* ws  = (float*)d_ws;

  __fp16* Eq  = (__fp16*)ws;
  __fp16* Ev  = (__fp16*)(ws + 2097152);
  __fp16* VT  = (__fp16*)(ws + 4194304);
  float*  S   = ws + 6291456;              // spans ..14680064
  float*  C   = ws;                        // reuse Eq+Ev (dead after score)
  __fp16* Gi2 = (__fp16*)(ws + 6291456);   // reuse S low half (dead after ctxsm)
  float*  hx  = ws + 14680064;             // PAST S's end (R10 overlap fix)
  unsigned* flags = (unsigned*)(ws + 14696448);  // 64 u32, past hx

  hipMemsetAsync(flags, 0, 64 * sizeof(unsigned), stream);

  proj_k<<<dim3(4, 256), 256, 0, stream>>>(v, Wp, Wp_, Eq, Ev);
  vt_k<<<dim3(8, 16, 32), 256, 0, stream>>>(v, VT);
  score_k<<<dim3(16, 8, 32), 256, 0, stream>>>(Eq, Ev, Vv, S);
  ctxsm_k<<<dim3(8, 32), 512, 0, stream>>>(S, VT, C);
  gi_k<<<dim3(12, 256), 256, 0, stream>>>(C, Wih, bih, bhh, Gi2);
  gru2_k<<<64, 512, 0, stream>>>(Gi2, Whh, bhh, h0, out, hx, flags);
}

// Round 13
// 880.428 us; speedup vs baseline: 4.7728x; 4.7728x over previous
//
#include <hip/hip_runtime.h>
#include <stdint.h>

// L=512, B=32, D=H=256
// Workspace (float offsets into 64MB d_ws):
//   Eq  f16[16384*256] @ 0
//   Ev  f16[16384*256] @ 2097152
//   VT  f16[32][256][512] @ 4194304
//   S   f32[32*512*512] @ 6291456   (raw scores; softmax fused into ctxsm_k)
//   C   f32[16384*256] @ 0          (reuse Eq+Ev, dead after score)
//   Gi2 f16[16384*768] @ 6291456    (reuse S, dead after ctxsm)

#define C2    2.8853900817779268f   // 2*log2(e)
#define LOG2E 1.4426950408889634f

typedef __fp16 f16x2 __attribute__((ext_vector_type(2)));
typedef __fp16 f16x4_t __attribute__((ext_vector_type(4)));
typedef __fp16 f16x8 __attribute__((ext_vector_type(8)));
typedef float f32x4 __attribute__((ext_vector_type(4)));

static __device__ __forceinline__ float rcp_f(float x)  { return __builtin_amdgcn_rcpf(x); }
static __device__ __forceinline__ float exp2_f(float x) { return __builtin_amdgcn_exp2f(x); }
#if __has_builtin(__builtin_amdgcn_rcph)
static __device__ __forceinline__ __fp16 rcph(__fp16 x) {
  return (__fp16)__builtin_amdgcn_rcph((_Float16)x);
}
#else
static __device__ __forceinline__ __fp16 rcph(__fp16 x) {
  return (__fp16)__builtin_amdgcn_rcpf((float)x);
}
#endif
static __device__ __forceinline__ float dot2f(f16x2 a, f16x2 b, float c) {
  return __builtin_amdgcn_fdot2(a, b, c, false);
}
static __device__ __forceinline__ f16x8 cvt8(float4 a, float4 b) {
  f16x8 f;
  f[0] = (__fp16)a.x; f[1] = (__fp16)a.y; f[2] = (__fp16)a.z; f[3] = (__fp16)a.w;
  f[4] = (__fp16)b.x; f[5] = (__fp16)b.y; f[6] = (__fp16)b.z; f[7] = (__fp16)b.w;
  return f;
}

// Fragment conventions (verified end-to-end):
//   A-frag: lane(col=lane&15, quad=lane>>4) holds A[m=col][k=quad*8+jj]
//   B-frag: lane holds B[k=quad*8+jj][n=col]
//   C/D:    row(m)=quad*4+reg, col(n)=lane&15

// ---------------------------------------------------------------------------
// Fused projections -> f16 with exponent clamp to f16-normal range.
// ---------------------------------------------------------------------------
__global__ __launch_bounds__(256) void proj_k(
    const float* __restrict__ v, const float* __restrict__ Wp,
    const float* __restrict__ Wp_, __fp16* __restrict__ Eq,
    __fp16* __restrict__ Ev)
{
  __shared__ __align__(16) __fp16 As[64][40];
  __shared__ __align__(16) __fp16 Wqs[64][40];
  __shared__ __align__(16) __fp16 Wvs[64][40];
  const int t = threadIdx.x, wave = t >> 6, lane = t & 63;
  const int quad = lane >> 4, col = lane & 15;
  const int n0 = blockIdx.x * 64, m0 = blockIdx.y * 64;
  const int srow = t >> 2, skq = t & 3;

  f32x4 accq[4], accv[4];
#pragma unroll
  for (int nt = 0; nt < 4; ++nt) {
    accq[nt] = (f32x4){0.f, 0.f, 0.f, 0.f};
    accv[nt] = (f32x4){0.f, 0.f, 0.f, 0.f};
  }

  for (int kc = 0; kc < 8; ++kc) {
    const int k0 = kc * 32;
    {
      const float4* ap = (const float4*)&v[(size_t)(m0 + srow) * 256 + k0 + skq * 8];
      *(f16x8*)&As[srow][skq * 8] = cvt8(ap[0], ap[1]);
      const float4* qp = (const float4*)&Wp[(size_t)(n0 + srow) * 256 + k0 + skq * 8];
      *(f16x8*)&Wqs[srow][skq * 8] = cvt8(qp[0], qp[1]);
      const float4* vp = (const float4*)&Wp_[(size_t)(n0 + srow) * 256 + k0 + skq * 8];
      *(f16x8*)&Wvs[srow][skq * 8] = cvt8(vp[0], vp[1]);
    }
    __syncthreads();
    f16x8 a = *(const f16x8*)&As[wave * 16 + col][quad * 8];
#pragma unroll
    for (int nt = 0; nt < 4; ++nt) {
      f16x8 bq = *(const f16x8*)&Wqs[nt * 16 + col][quad * 8];
      f16x8 bv = *(const f16x8*)&Wvs[nt * 16 + col][quad * 8];
      accq[nt] = __builtin_amdgcn_mfma_f32_16x16x32_f16(a, bq, accq[nt], 0, 0, 0);
      accv[nt] = __builtin_amdgcn_mfma_f32_16x16x32_f16(a, bv, accv[nt], 0, 0, 0);
    }
    __syncthreads();
  }

#pragma unroll
  for (int nt = 0; nt < 4; ++nt)
#pragma unroll
    for (int r = 0; r < 4; ++r) {
      size_t m = m0 + wave * 16 + quad * 4 + r;
      size_t n = n0 + nt * 16 + col;
      float eq = C2 * accq[nt][r], ev = C2 * accv[nt][r];
      eq = fminf(fmaxf(eq, -14.f), 15.5f);
      ev = fminf(fmaxf(ev, -14.f), 15.5f);
      Eq[m * 256 + n] = (__fp16)exp2_f(eq);
      Ev[m * 256 + n] = (__fp16)exp2_f(ev);
    }
}

// ---------------------------------------------------------------------------
// v transpose: VT[b][d][l] (f16) from v[l][b][d] (f32). 32x32 LDS tiles.
// ---------------------------------------------------------------------------
__global__ __launch_bounds__(256) void vt_k(
    const float* __restrict__ v, __fp16* __restrict__ VT)
{
  __shared__ float Ts[32][33];
  const int t = threadIdx.x;
  const int d0 = blockIdx.x * 32, l0 = blockIdx.y * 32, b = blockIdx.z;
  {
    int lrow = t >> 3, dq = t & 7;
    float4 a = *(const float4*)&v[((size_t)(l0 + lrow) * 32 + b) * 256 + d0 + dq * 4];
    Ts[dq * 4 + 0][lrow] = a.x; Ts[dq * 4 + 1][lrow] = a.y;
    Ts[dq * 4 + 2][lrow] = a.z; Ts[dq * 4 + 3][lrow] = a.w;
  }
  __syncthreads();
  {
    int drow = t >> 3, lq = t & 7;
    f16x4_t o;
#pragma unroll
    for (int e = 0; e < 4; ++e) o[e] = (__fp16)Ts[drow][lq * 4 + e];
    *(f16x4_t*)&VT[((size_t)b * 256 + d0 + drow) * 512 + l0 + lq * 4] = o;
  }
}

// ---------------------------------------------------------------------------
// Packed-f16 score: S[b][i][l] = -2 * sum_h V[b][h] * rcp(1 + Eq*Ev).
// ---------------------------------------------------------------------------
__global__ __launch_bounds__(256) void score_k(
    const __fp16* __restrict__ Eq, const __fp16* __restrict__ Ev,
    const float* __restrict__ Vvec, float* __restrict__ S)
{
  __shared__ __align__(16) __fp16 Eqs[64][72];
  __shared__ __align__(16) __fp16 Evs[32][72];
  __shared__ __align__(16) __fp16 Vs[256];
  const int t = threadIdx.x;
  const int tx = t & 15, ty = t >> 4;
  const int l0 = blockIdx.x * 32;
  const int i0 = blockIdx.y * 64;
  const int b  = blockIdx.z;

  Vs[t] = (__fp16)(-2.0f * Vvec[b * 256 + t]);
  float acc[4][2] = {};
  const f16x2 one2 = {(__fp16)1.f, (__fp16)1.f};

  for (int st = 0; st < 4; ++st) {
    const int h0 = st * 64;
#pragma unroll
    for (int s = 0; s < 2; ++s) {
      int f = t + s * 256;
      int row = f >> 3, cq = f & 7;
      *(f16x8*)&Eqs[row][cq * 8] =
          *(const f16x8*)&Eq[((size_t)(i0 + row) * 32 + b) * 256 + h0 + cq * 8];
    }
    {
      int row = t >> 3, cq = t & 7;
      *(f16x8*)&Evs[row][cq * 8] =
          *(const f16x8*)&Ev[((size_t)(l0 + row) * 32 + b) * 256 + h0 + cq * 8];
    }
    __syncthreads();

#pragma unroll
    for (int k8 = 0; k8 < 8; ++k8) {
      f16x8 vh8 = *(const f16x8*)&Vs[h0 + k8 * 8];
      f16x8 ev80 = *(const f16x8*)&Evs[tx][k8 * 8];
      f16x8 ev81 = *(const f16x8*)&Evs[tx + 16][k8 * 8];
      f16x8 eq8[4];
#pragma unroll
      for (int r = 0; r < 4; ++r)
        eq8[r] = *(const f16x8*)&Eqs[ty * 4 + r][k8 * 8];
#pragma unroll
      for (int q = 0; q < 4; ++q) {
        f16x2 vh2 = {vh8[q * 2], vh8[q * 2 + 1]};
        f16x2 e0  = {ev80[q * 2], ev80[q * 2 + 1]};
        f16x2 e1  = {ev81[q * 2], ev81[q * 2 + 1]};
#pragma unroll
        for (int r = 0; r < 4; ++r) {
          f16x2 eq2 = {eq8[r][q * 2], eq8[r][q * 2 + 1]};
          f16x2 d0 = eq2 * e0 + one2;   // v_pk_fma_f16
          f16x2 d1 = eq2 * e1 + one2;
          f16x2 r0 = {rcph(d0[0]), rcph(d0[1])};
          f16x2 r1 = {rcph(d1[0]), rcph(d1[1])};
          acc[r][0] = dot2f(vh2, r0, acc[r][0]);
          acc[r][1] = dot2f(vh2, r1, acc[r][1]);
        }
      }
    }
    __syncthreads();
  }

#pragma unroll
  for (int r = 0; r < 4; ++r) {
    float* ps = &S[((size_t)b * 512 + i0 + ty * 4 + r) * 512 + l0];
    ps[tx]      = acc[r][0];
    ps[tx + 16] = acc[r][1];
  }
}

// ---------------------------------------------------------------------------
// FUSED softmax + context: C[i][b][d] = sum_l softmax_l(S[b][i][:])[l] * VT[b][d][l].
// ---------------------------------------------------------------------------
__global__ __launch_bounds__(512) void ctxsm_k(
    const float* __restrict__ S, const __fp16* __restrict__ VT,
    float* __restrict__ C)
{
  __shared__ __align__(16) __fp16 As[64][40];
  __shared__ __align__(16) __fp16 Vs[256][40];
  __shared__ float red[64][8];
  __shared__ float stat_m[64], stat_inv[64];
  const int t = threadIdx.x, wave = t >> 6, lane = t & 63;
  const int quad = lane >> 4, col = lane & 15;
  const int i0 = blockIdx.x * 64, b = blockIdx.y;
  const int mt = wave & 3, nh = wave >> 2;

  // ---- phase 1: row stats ----
  {
    const int row = t >> 3, seg = t & 7;
    const float* sp = &S[((size_t)b * 512 + i0 + row) * 512 + seg * 64];
    float m = -1e30f;
#pragma unroll
    for (int u = 0; u < 16; ++u) {
      float4 x = *(const float4*)&sp[u * 4];
      m = fmaxf(m, fmaxf(fmaxf(x.x, x.y), fmaxf(x.z, x.w)));
    }
    red[row][seg] = m;
    __syncthreads();
    if (seg == 0) {
      float mm = red[row][0];
#pragma unroll
      for (int u = 1; u < 8; ++u) mm = fmaxf(mm, red[row][u]);
      stat_m[row] = mm;
    }
    __syncthreads();
    float M = stat_m[row];
    float s = 0.f;
#pragma unroll
    for (int u = 0; u < 16; ++u) {
      float4 x = *(const float4*)&sp[u * 4];
      s += exp2_f(LOG2E * (x.x - M)) + exp2_f(LOG2E * (x.y - M)) +
           exp2_f(LOG2E * (x.z - M)) + exp2_f(LOG2E * (x.w - M));
    }
    red[row][seg] = s;
    __syncthreads();
    if (seg == 0) {
      float ss = red[row][0];
#pragma unroll
      for (int u = 1; u < 8; ++u) ss += red[row][u];
      stat_inv[row] = rcp_f(ss);
    }
    __syncthreads();
  }

  // ---- phase 2: MFMA with softmax applied at A staging ----
  f32x4 acc[8];
#pragma unroll
  for (int n = 0; n < 8; ++n) acc[n] = (f32x4){0.f, 0.f, 0.f, 0.f};

  for (int kc = 0; kc < 16; ++kc) {
    const int l0 = kc * 32;
    {
      int arow = t >> 3, aq = t & 7;
      float M = stat_m[arow], inv = stat_inv[arow];
      float4 x = *(const float4*)&S[((size_t)b * 512 + i0 + arow) * 512 + l0 + aq * 4];
      f16x4_t o;
      o[0] = (__fp16)(exp2_f(LOG2E * (x.x - M)) * inv);
      o[1] = (__fp16)(exp2_f(LOG2E * (x.y - M)) * inv);
      o[2] = (__fp16)(exp2_f(LOG2E * (x.z - M)) * inv);
      o[3] = (__fp16)(exp2_f(LOG2E * (x.w - M)) * inv);
      *(f16x4_t*)&As[arow][aq * 4] = o;
#pragma unroll
      for (int s2 = 0; s2 < 2; ++s2) {
        int f = t + s2 * 512;
        int vrow = f >> 2, vq = f & 3;
        *(f16x8*)&Vs[vrow][vq * 8] =
            *(const f16x8*)&VT[((size_t)b * 256 + vrow) * 512 + l0 + vq * 8];
      }
    }
    __syncthreads();
    f16x8 a = *(const f16x8*)&As[mt * 16 + col][quad * 8];
#pragma unroll
    for (int n = 0; n < 8; ++n) {
      f16x8 vf = *(const f16x8*)&Vs[nh * 128 + n * 16 + col][quad * 8];
      acc[n] = __builtin_amdgcn_mfma_f32_16x16x32_f16(a, vf, acc[n], 0, 0, 0);
    }
    __syncthreads();
  }

#pragma unroll
  for (int n = 0; n < 8; ++n)
#pragma unroll
    for (int r = 0; r < 4; ++r) {
      size_t i = i0 + mt * 16 + quad * 4 + r;
      size_t d = nh * 128 + n * 16 + col;
      C[(i * 32 + b) * 256 + d] = acc[n][r];
    }
}

// ---------------------------------------------------------------------------
// Gi2 = f16( C @ Wih^T + bih (+bhh for gates r,z) ). M=16384, N=768, K=256.
// ---------------------------------------------------------------------------
__global__ __launch_bounds__(256) void gi_k(
    const float* __restrict__ A, const float* __restrict__ W,
    const float* __restrict__ bih, const float* __restrict__ bhh,
    __fp16* __restrict__ G)
{
  __shared__ __align__(16) __fp16 As[64][40];
  __shared__ __align__(16) __fp16 Ws[64][40];
  const int t = threadIdx.x, wave = t >> 6, lane = t & 63;
  const int quad = lane >> 4, col = lane & 15;
  const int n0 = blockIdx.x * 64, m0 = blockIdx.y * 64;
  const int srow = t >> 2, skq = t & 3;

  f32x4 acc[4];
#pragma unroll
  for (int nt = 0; nt < 4; ++nt) acc[nt] = (f32x4){0.f, 0.f, 0.f, 0.f};

  for (int kc = 0; kc < 8; ++kc) {
    const int k0 = kc * 32;
    {
      const float4* ap = (const float4*)&A[(size_t)(m0 + srow) * 256 + k0 + skq * 8];
      *(f16x8*)&As[srow][skq * 8] = cvt8(ap[0], ap[1]);
      const float4* wp = (const float4*)&W[(size_t)(n0 + srow) * 256 + k0 + skq * 8];
      *(f16x8*)&Ws[srow][skq * 8] = cvt8(wp[0], wp[1]);
    }
    __syncthreads();
    f16x8 a = *(const f16x8*)&As[wave * 16 + col][quad * 8];
#pragma unroll
    for (int nt = 0; nt < 4; ++nt) {
      f16x8 b = *(const f16x8*)&Ws[nt * 16 + col][quad * 8];
      acc[nt] = __builtin_amdgcn_mfma_f32_16x16x32_f16(a, b, acc[nt], 0, 0, 0);
    }
    __syncthreads();
  }

#pragma unroll
  for (int nt = 0; nt < 4; ++nt) {
    int n = n0 + nt * 16 + col;
    float bias = bih[n] + (n < 512 ? bhh[n] : 0.f);
#pragma unroll
    for (int r = 0; r < 4; ++r) {
      size_t m = m0 + wave * 16 + quad * 4 + r;
      G[m * 768 + n] = (__fp16)(acc[nt][r] + bias);
    }
  }
}

// ---------------------------------------------------------------------------
// R12: FINAL — revert to the verified R9 MFMA GRU (gru_k 517us, total 883us,
// absmax 0.0254, bank conflicts 0, MfmaUtil 7.8).
// R11 post-mortem: pair-split protocol was made correct (workspace fix held
// under graph replay) but cost 3850us — VGPR_Count=36 shows the in-loop
// atomics/spin made the compiler sink the Bf weight loads into the loop
// (FETCH 20.8->32.6MB), and the cross-CU release/acquire round-trip is
// ~18000 cyc/iter, an order of magnitude above the 931-cyc MFMA saving.
// Structural ledger (12 rounds):
//  - gru_k = 2420 cyc/iter vs 1862-cyc MFMA-issue floor (77%); tail is the
//    serial recurrence skeleton (LDS h round-trip + dependent gate chain +
//    barrier at 2-wave lockstep).
//  - Register-resident VALU-dot2: impossible (Whh 384KB > 256KB reg file per
//    block at any block size; grant law = 65536 regs/block; R4-R7).
//  - MFMA||VALU hybrid: bank conflicts + register overflow (R8).
//  - Cross-CU pair-split: exchange >> savings (R10/R11).
// This decomposition is at its practical ceiling.
// ---------------------------------------------------------------------------
__global__ __launch_bounds__(512, 1) void gru_k(
    const __fp16* __restrict__ Gi2, const float* __restrict__ Whh,
    const float* __restrict__ bhh, const float* __restrict__ h0,
    float* __restrict__ out)
{
  __shared__ __align__(16) __fp16 hA[2][256];
  const int t = threadIdx.x, wave = t >> 6, lane = t & 63;
  const int quad = lane >> 4, col = lane & 15;
  const int b = blockIdx.x;
  const int jw = wave * 32;
  const int pa = quad >> 1;                 // this lane's assigned p slice
  const int ja = jw + pa * 16 + col;        // this lane's assigned j
  const bool writer = (quad & 1) == 0;      // quads 0 and 2 write

  f16x8 Bf[2][3][8];
#pragma unroll
  for (int p = 0; p < 2; ++p)
#pragma unroll
    for (int g = 0; g < 3; ++g) {
      const float* wrow = &Whh[(size_t)(g * 256 + jw + p * 16 + col) * 256];
#pragma unroll
      for (int kk = 0; kk < 8; ++kk) {
        const float4* wp = (const float4*)&wrow[kk * 32 + quad * 8];
        Bf[p][g][kk] = cvt8(wp[0], wp[1]);
      }
    }

  const float bn = bhh[512 + ja];
  float hold;
  {
    float h = h0[(size_t)b * 256 + ja];
    hold = h;
    if (writer) hA[0][ja] = (__fp16)h;
  }
  __syncthreads();

  // per-lane Gi2 pointer: Gi2[(i*32+b)*768 + g*256 + ja]; row stride 24576.
  const __fp16* gp = &Gi2[(size_t)b * 768 + ja];
  __fp16 gcur[3];
#pragma unroll
  for (int g = 0; g < 3; ++g) gcur[g] = gp[g * 256];
  const __fp16* gq = gp + 24576;            // row i=1

  float* outp = &out[(size_t)b * 256 + ja];

  for (int i = 0; i < 512; ++i) {
    // prefetch next Gi2 row; gate stride 256 halfs (matches gi_k layout)
    __fp16 gnext[3];
    gnext[0] = gq[0];
    gnext[1] = gq[256];
    gnext[2] = gq[512];
    gq += 24576;

    const __fp16* hbuf = hA[i & 1];

    // k-chunk 0 starts the acc chain from a loop-invariant zero C
    f32x4 acc[2][3];
    {
      f16x8 a = *(const f16x8*)&hbuf[quad * 8];
#pragma unroll
      for (int p = 0; p < 2; ++p)
#pragma unroll
        for (int g = 0; g < 3; ++g)
          acc[p][g] = __builtin_amdgcn_mfma_f32_16x16x32_f16(
              a, Bf[p][g][0], (f32x4){0.f, 0.f, 0.f, 0.f}, 0, 0, 0);
    }
#pragma unroll
    for (int kk = 1; kk < 8; ++kk) {
      f16x8 a = *(const f16x8*)&hbuf[kk * 32 + quad * 8];
#pragma unroll
      for (int p = 0; p < 2; ++p)
#pragma unroll
        for (int g = 0; g < 3; ++g)
          acc[p][g] = __builtin_amdgcn_mfma_f32_16x16x32_f16(
              a, Bf[p][g][kk], acc[p][g], 0, 0, 0);
    }

    // lane-split gate math: one j per lane (quads 1,3 redundant with 0,2)
    float ar = pa ? acc[1][0][0] : acc[0][0][0];
    float az = pa ? acc[1][1][0] : acc[0][1][0];
    float an = pa ? acc[1][2][0] : acc[0][2][0];
    float rr = rcp_f(1.f + exp2_f(-LOG2E * ((float)gcur[0] + ar)));
    float zz = rcp_f(1.f + exp2_f(-LOG2E * ((float)gcur[1] + az)));
    float na = fmaf(rr, an + bn, (float)gcur[2]);
    float nn = fmaf(-2.f, rcp_f(1.f + exp2_f(C2 * na)), 1.f);
    float h  = fmaf(zz, hold - nn, nn);
    hold = h;

    __fp16* hnext = hA[(i + 1) & 1];
    if (writer) {
      outp[0] = h;
      hnext[ja] = (__fp16)h;
    }
    outp += 8192;

    gcur[0] = gnext[0]; gcur[1] = gnext[1]; gcur[2] = gnext[2];

    // raw barrier: order LDS hand-off only; do NOT drain vmcnt (out stores
    // and gnext loads stay in flight; compiler's counted vmcnt covers loads).
    asm volatile("s_waitcnt lgkmcnt(0)" ::: "memory");
    __builtin_amdgcn_s_barrier();
    asm volatile("" ::: "memory");
  }
}

// ---------------------------------------------------------------------------
extern "C" void kernel_launch(void* const* d_in, const int* in_sizes, int n_in,
                              void* d_out, int out_size, void* d_ws, size_t ws_size,
                              hipStream_t stream)
{
  const float* v   = (const float*)d_in[0];
  const float* h0  = (const float*)d_in[1];
  const float* Vv  = (const float*)d_in[2];
  const float* Wp  = (const float*)d_in[3];
  const float* Wp_ = (const float*)d_in[4];
  const float* Wih = (const float*)d_in[5];
  const float* Whh = (const float*)d_in[6];
  const float* bih = (const float*)d_in[7];
  const float* bhh = (const float*)d_in[8];
  float* out = (float*)d_out;
  float* ws  = (float*)d_ws;

  __fp16* Eq  = (__fp16*)ws;
  __fp16* Ev  = (__fp16*)(ws + 2097152);
  __fp16* VT  = (__fp16*)(ws + 4194304);
  float*  S   = ws + 6291456;
  float*  C   = ws;                        // reuse Eq+Ev (dead after score)
  __fp16* Gi2 = (__fp16*)(ws + 6291456);   // reuse S (dead after ctxsm)

  proj_k<<<dim3(4, 256), 256, 0, stream>>>(v, Wp, Wp_, Eq, Ev);
  vt_k<<<dim3(8, 16, 32), 256, 0, stream>>>(v, VT);
  score_k<<<dim3(16, 8, 32), 256, 0, stream>>>(Eq, Ev, Vv, S);
  ctxsm_k<<<dim3(8, 32), 512, 0, stream>>>(S, VT, C);
  gi_k<<<dim3(12, 256), 256, 0, stream>>>(C, Wih, bih, bhh, Gi2);
  gru_k<<<32, 512, 0, stream>>>(Gi2, Whh, bhh, h0, out);
}